// Round 10
// baseline (218.590 us; speedup 1.0000x reference)
//
#include <hip/hip_runtime.h>
#include <math.h>

#define N_ATOMS  100000
#define N_BOND   150000
#define N_ANGLE  200000
#define N_IMP     50000
#define N_PROP   100000
#define M3       (3 * N_ATOMS)          // 300000 coordinate rows

#define GSTRIDE  (N_ATOMS * 8)          // dwords per batch-group slab (3.2 MB, fits 4MB XCD L2)
#define N_TILES  (N_ATOMS / 32)         // 3125 transpose tiles

#define EPS_GUARD 1e-12f                // fp8 collision guard

// ---- wave partition within a batch-group: 1536 blocks -> 192 blocks/group
// ---- -> 768 waves/group, type-specialized (counts ~ VALU cost). (256,6).
// ---- TRIP must be == 2 (mod 3) for the depth-3 pipeline.
#define WB_B 84                          // bond  waves/group, trip 38 (3192>=3125)
#define WB_A 297                         // angle waves/group, trip 23 (6831>=6250)
#define WB_I 146                         // improper,          trip 23 (3358>=3125)
#define WB_P 241                         // proper,            trip 26 (6266>=6250)
#define OFF_A (WB_B)                     // 84
#define OFF_I (WB_B + WB_A)              // 381
#define OFF_P (WB_B + WB_A + WB_I)       // 527

// d_ws layout (bytes): pos8 @0 (25.6MB, group-major); fused params after
#define OFF_BONDP (26u << 20)
#define OFF_ANGP  (29u << 20)
#define OFF_IMPP  (31u << 20)
#define OFF_PROPP (32u << 20)

typedef float v2f __attribute__((ext_vector_type(2)));
struct V3P { v2f x, y, z; };             // 3D vector for a batch-PAIR (lo,hi)

__device__ __forceinline__ int imin(int a, int b) { return (a < b) ? a : b; }

__device__ __forceinline__ V3P subP(V3P a, V3P b) { return V3P{a.x-b.x, a.y-b.y, a.z-b.z}; }
__device__ __forceinline__ v2f dotP(V3P a, V3P b) { return a.x*b.x + a.y*b.y + a.z*b.z; }
__device__ __forceinline__ V3P scaleP(V3P a, v2f s) { return V3P{a.x*s, a.y*s, a.z*s}; }
__device__ __forceinline__ V3P crossP(V3P a, V3P b) {
    return V3P{a.y*b.z - a.z*b.y, a.z*b.x - a.x*b.z, a.x*b.y - a.y*b.x};
}

__device__ __forceinline__ float grcp(float x) { return __builtin_amdgcn_rcpf(fmaxf(x, EPS_GUARD)); }
__device__ __forceinline__ float grsq(float x) { return __builtin_amdgcn_rsqf(fmaxf(x, EPS_GUARD)); }

__device__ __forceinline__ float fast_acos(float x) {
    float ax = fabsf(x);
    float r  = sqrtf(fmaxf(0.0f, 1.0f - ax));
    float p  = fmaf(fmaf(fmaf(-0.0187293f, ax, 0.0742610f), ax, -0.2121144f), ax, 1.5707288f);
    float v  = r * p;
    return (x < 0.0f) ? (3.14159265358979f - v) : v;
}

__device__ __forceinline__ float fast_atan2(float y, float x) {
    float ax = fabsf(x), ay = fabsf(y);
    float mn = fminf(ax, ay), mx = fmaxf(ax, ay);
    float a  = mn * grcp(mx);
    float s  = a * a;
    float p  = fmaf(s, fmaf(s, fmaf(s, fmaf(s, fmaf(s, -0.01172120f, 0.05265332f),
                     -0.11643287f), 0.19354346f), -0.33262347f), 0.99997726f);
    float t  = a * p;
    if (ay > ax)  t = 1.57079632679490f - t;
    if (x < 0.0f) t = 3.14159265358979f - t;
    return copysignf(t, y);
}

// unpack a batch-pair: w.x = fp8x4 coords of batch lo, w.y = batch hi
__device__ __forceinline__ V3P unpackP(uint2 w) {
    v2f lo = __builtin_amdgcn_cvt_pk_f32_fp8((int)w.x, false);
    v2f hi = __builtin_amdgcn_cvt_pk_f32_fp8((int)w.y, false);
    float lz = __builtin_amdgcn_cvt_f32_fp8((int)w.x, 2);
    float hz = __builtin_amdgcn_cvt_f32_fp8((int)w.y, 2);
    V3P r;
    r.x = (v2f){lo.x, hi.x};
    r.y = (v2f){lo.y, hi.y};
    r.z = (v2f){lz,   hz};
    return r;
}

// ---- fused pre-pass: transpose+quantize + param fusion + out zeroing ----
__global__ __launch_bounds__(256) void pre_kernel(
    const float* __restrict__ pos, unsigned int* __restrict__ pos8,
    const int* __restrict__ bond_type,     const float* __restrict__ equ_bond,
    const float* __restrict__ k_bond,
    const int* __restrict__ angle_type,    const float* __restrict__ equ_angle,
    const float* __restrict__ k_angle,
    const int* __restrict__ improper_type, const float* __restrict__ equ_improper,
    const float* __restrict__ k_improper,
    const float* __restrict__ proper_const, const float* __restrict__ proper_mul,
    const float* __restrict__ proper_phase,
    float2* __restrict__ bondP, float2* __restrict__ angleP,
    float2* __restrict__ impP,  float4* __restrict__ propP,
    float* __restrict__ out, int out_n)
{
    __shared__ float tile[64][97];
    if (blockIdx.x < N_TILES) {
        const int t    = threadIdx.x;
        const int b    = t >> 2;
        const int j    = t & 3;
        const int lane = t & 63;
        const int wa   = t >> 6;
        const int a0   = blockIdx.x * 32;

        const float* __restrict__ src = pos + (size_t)b * M3 + 3 * a0;
        #pragma unroll
        for (int i = 0; i < 6; ++i) {
            const int f4 = j + 4 * i;
            const float4 v = *(const float4*)(src + 4 * f4);
            tile[b][4*f4 + 0] = v.x;
            tile[b][4*f4 + 1] = v.y;
            tile[b][4*f4 + 2] = v.z;
            tile[b][4*f4 + 3] = v.w;
        }
        __syncthreads();

        const int jj = lane & 7;
        const int as = lane >> 3;
        const int al = wa * 8 + as;
        #pragma unroll
        for (int g = 0; g < 8; ++g) {
            const int bb = g * 8 + jj;
            int wd = 0;
            wd = __builtin_amdgcn_cvt_pk_fp8_f32(tile[bb][3*al + 0], tile[bb][3*al + 1], wd, false);
            wd = __builtin_amdgcn_cvt_pk_fp8_f32(tile[bb][3*al + 2], 0.0f, wd, true);
            pos8[(size_t)g * GSTRIDE + (size_t)(a0 + al) * 8 + jj] = (unsigned int)wd;
        }
    } else {
        const int i = (blockIdx.x - N_TILES) * 256 + threadIdx.x;
        if (i < out_n)   out[i] = 0.0f;      // replaces the hipMemsetAsync dispatch
        if (i < N_BOND)  { int t = bond_type[i];     bondP[i]  = make_float2(equ_bond[t],     k_bond[t]); }
        if (i < N_ANGLE) { int t = angle_type[i];    angleP[i] = make_float2(equ_angle[t],    k_angle[t]); }
        if (i < N_IMP)   { int t = improper_type[i]; impP[i]   = make_float2(equ_improper[t], k_improper[t]); }
        if (i < N_PROP)  { propP[i] = make_float4(proper_const[i], proper_mul[i], proper_phase[i], 0.0f); }
    }
}

// ---- uint2 gathers: lane = 16 term-slots x 4 batch-pairs; 8B (2 batches)/lane
template<int NW>
__device__ __forceinline__ void gath(const unsigned int* __restrict__ baseg,
                                     const int* ii, int jp, uint2* wv) {
    #pragma unroll
    for (int k = 0; k < NW; ++k)
        wv[k] = *(const uint2*)(baseg + (size_t)((unsigned)ii[k] * 8u + (unsigned)(jp * 2)));
}

// ---- type tags: q in [0,16); params PREFETCHED into registers (pp) at the
// ---- same pipeline distance as indices -> comp() is pure register math.
struct BondT {                                 // 48 terms/chunk: 16 slots x 3 terms
    static constexpr int NC = 3125, NI = 6, NW = 6, NP = 6;
    __device__ static void loadIdx(const int* __restrict__ idcs, int l, int q, int* ii) {
        const int2* p = (const int2*)idcs + (l * 48 + q * 3);   // 3 pairs
        int2 a = p[0], b = p[1], c = p[2];
        ii[0]=a.x; ii[1]=a.y; ii[2]=b.x; ii[3]=b.y; ii[4]=c.x; ii[5]=c.y;
    }
    __device__ static void loadPrm(const float* __restrict__ prm, int l, int q, float* pp) {
        const float2* b = (const float2*)prm + (l * 48 + q * 3);  // 3 x (eq,k), 8B-aligned
        float2 p0 = b[0], p1 = b[1], p2 = b[2];
        pp[0]=p0.x; pp[1]=p0.y; pp[2]=p1.x; pp[3]=p1.y; pp[4]=p2.x; pp[5]=p2.y;
    }
    __device__ static v2f comp(const uint2* wv, const float* pp) {
        v2f ec = {0.0f, 0.0f};
        #pragma unroll
        for (int i = 0; i < 3; ++i) {
            V3P dv = subP(unpackP(wv[2*i]), unpackP(wv[2*i + 1]));
            v2f d2 = dotP(dv, dv);
            v2f d  = (v2f){sqrtf(d2.x), sqrtf(d2.y)};
            v2f dd = d - pp[2*i];
            ec += pp[2*i + 1] * (dd * dd);
        }
        return ec;
    }
};

struct AngleT {                                // 32 terms/chunk: 16 slots x 2 terms
    static constexpr int NC = 6250, NI = 6, NW = 6, NP = 4;
    __device__ static void loadIdx(const int* __restrict__ idcs, int l, int q, int* ii) {
        const int2* p = (const int2*)idcs + (l * 48 + q * 3);   // 2 terms x 3 ints
        int2 a = p[0], b = p[1], c = p[2];
        ii[0]=a.x; ii[1]=a.y; ii[2]=b.x; ii[3]=b.y; ii[4]=c.x; ii[5]=c.y;
    }
    __device__ static void loadPrm(const float* __restrict__ prm, int l, int q, float* pp) {
        const float4 P = *((const float4*)prm + (l * 16 + q));  // 2 x (eq,k), 16B-aligned
        pp[0]=P.x; pp[1]=P.y; pp[2]=P.z; pp[3]=P.w;
    }
    __device__ static v2f comp(const uint2* wv, const float* pp) {
        v2f ec = {0.0f, 0.0f};
        #pragma unroll
        for (int i = 0; i < 2; ++i) {
            const float eq = pp[2*i];
            const float kk = pp[2*i + 1];
            V3P pm = unpackP(wv[3*i + 1]);
            V3P v1 = subP(unpackP(wv[3*i]),     pm);
            V3P v2 = subP(unpackP(wv[3*i + 2]), pm);
            v2f num = dotP(v1, v2);
            v2f nn  = dotP(v1, v1) * dotP(v2, v2);
            float clo = fminf(1.0f, fmaxf(-1.0f, num.x * grsq(nn.x)));
            float chi = fminf(1.0f, fmaxf(-1.0f, num.y * grsq(nn.y)));
            v2f dd = (v2f){fast_acos(clo), fast_acos(chi)} - eq;
            ec += kk * (dd * dd);
        }
        return ec;
    }
};

struct ImpT {                                  // 16 terms/chunk: 16 slots x 1 term
    static constexpr int NC = 3125, NI = 4, NW = 4, NP = 2;
    __device__ static void loadIdx(const int* __restrict__ idcs, int l, int q, int* ii) {
        const int4 p = *((const int4*)idcs + (l * 16 + q));
        ii[0]=p.x; ii[1]=p.y; ii[2]=p.z; ii[3]=p.w;
    }
    __device__ static void loadPrm(const float* __restrict__ prm, int l, int q, float* pp) {
        const float2 P = ((const float2*)prm)[l * 16 + q];
        pp[0]=P.x; pp[1]=P.y;
    }
    __device__ static v2f comp(const uint2* wv, const float* pp) {
        V3P a0 = unpackP(wv[0]);
        V3P a1 = unpackP(wv[1]);
        V3P a2 = unpackP(wv[2]);
        V3P a3 = unpackP(wv[3]);
        V3P b0 = subP(a0, a1);
        V3P b1 = subP(a2, a1);
        V3P b2 = subP(a3, a2);
        v2f nb1 = dotP(b1, b1);
        v2f inv = (v2f){grsq(nb1.x), grsq(nb1.y)};
        b1 = scaleP(b1, inv);
        V3P v  = subP(b0, scaleP(b1, dotP(b0, b1)));
        V3P w3 = subP(b2, scaleP(b1, dotP(b2, b1)));
        v2f x = dotP(v, w3);
        v2f y = dotP(crossP(b1, v), w3);
        v2f dd = (v2f){fast_atan2(y.x, x.x), fast_atan2(y.y, x.y)} - pp[0];
        return pp[1] * (dd * dd);
    }
};

struct PropT {                                 // 16 terms/chunk: 16 slots x 1 term
    static constexpr int NC = 6250, NI = 4, NW = 4, NP = 4;
    __device__ static void loadIdx(const int* __restrict__ idcs, int l, int q, int* ii) {
        const int4 p = *((const int4*)idcs + (l * 16 + q));
        ii[0]=p.x; ii[1]=p.y; ii[2]=p.z; ii[3]=p.w;
    }
    __device__ static void loadPrm(const float* __restrict__ prm, int l, int q, float* pp) {
        const float4 P = ((const float4*)prm)[l * 16 + q];      // (pc, pm, ph, 0)
        pp[0]=P.x; pp[1]=P.y; pp[2]=P.z; pp[3]=P.w;
    }
    __device__ static v2f comp(const uint2* wv, const float* pp) {
        V3P a0 = unpackP(wv[0]);
        V3P a1 = unpackP(wv[1]);
        V3P a2 = unpackP(wv[2]);
        V3P a3 = unpackP(wv[3]);
        V3P b0 = subP(a0, a1);
        V3P b1 = subP(a2, a1);
        V3P b2 = subP(a3, a2);
        if (pp[1] == 2.0f && pp[2] == 0.0f) {                   // uniform branch (per-term)
            v2f u   = dotP(b1, b1);
            v2f inv = (v2f){grcp(u.x), grcp(u.y)};
            V3P v  = subP(b0, scaleP(b1, dotP(b0, b1) * inv));
            V3P w3 = subP(b2, scaleP(b1, dotP(b2, b1) * inv));
            v2f x  = dotP(v, w3);
            v2f yp = dotP(crossP(b1, v), w3);
            v2f tt = u * x * x;
            v2f den = tt + yp * yp;
            return (2.0f * pp[0]) * tt * (v2f){grcp(den.x), grcp(den.y)};
        } else {
            v2f nb1 = dotP(b1, b1);
            v2f inv = (v2f){grsq(nb1.x), grsq(nb1.y)};
            b1 = scaleP(b1, inv);
            V3P v  = subP(b0, scaleP(b1, dotP(b0, b1)));
            V3P w3 = subP(b2, scaleP(b1, dotP(b2, b1)));
            v2f x = dotP(v, w3);
            v2f y = dotP(crossP(b1, v), w3);
            float plo = fast_atan2(y.x, x.x);
            float phi = fast_atan2(y.y, x.y);
            return pp[0] * ((v2f){1.0f + cosf(pp[1] * plo - pp[2]), 1.0f + cosf(pp[1] * phi - pp[2])});
        }
    }
};

// ---- depth-3 rotating pipeline with idx AND param prefetch (3 named buffer
// ---- sets, static indexing, unconditional writes). comp() = pure reg math.
// ---- Source order: comp consumes pp_k BEFORE the same-step refill of pp_k.
template<class T, int W, int TRIP>
__device__ __forceinline__ void run_type(const unsigned int* __restrict__ baseg,
                                         const int* __restrict__ idcs,
                                         const float* __restrict__ prm,
                                         int widx, int q, int jp, v2f& e)
{
    static_assert(TRIP % 3 == 2, "TRIP must be 2 mod 3");
    constexpr int NTRI = (TRIP - 2) / 3;
    constexpr int NCm1 = T::NC - 1;
    int   ii0[T::NI], ii1[T::NI], ii2[T::NI];
    float pp0[T::NP], pp1[T::NP], pp2[T::NP];
    uint2 wv0[T::NW], wv1[T::NW], wv2[T::NW];

    int c0 = widx;                       // widx < W <= NC: chunk c0 always valid
    T::loadIdx(idcs, c0, q, ii0);                    T::loadPrm(prm, c0, q, pp0);
    T::loadIdx(idcs, imin(c0 + W, NCm1), q, ii1);    T::loadPrm(prm, imin(c0 + W, NCm1), q, pp1);
    T::loadIdx(idcs, imin(c0 + 2 * W, NCm1), q, ii2);T::loadPrm(prm, imin(c0 + 2 * W, NCm1), q, pp2);
    gath<T::NW>(baseg, ii0, jp, wv0);
    gath<T::NW>(baseg, ii1, jp, wv1);

    #pragma unroll 1
    for (int p = 0; p < NTRI; ++p) {
        // step 0: compute c0 (wv0,pp0); gather c0+2W; refill slot0 <- c0+3W
        gath<T::NW>(baseg, ii2, jp, wv2);
        v2f ec = T::comp(wv0, pp0);
        T::loadIdx(idcs, imin(c0 + 3 * W, NCm1), q, ii0);
        T::loadPrm(prm, imin(c0 + 3 * W, NCm1), q, pp0);
        e += ((c0 <= NCm1) ? 1.0f : 0.0f) * ec;

        // step 1: compute c0+W (wv1,pp1); gather c0+3W; refill slot1 <- c0+4W
        gath<T::NW>(baseg, ii0, jp, wv0);
        ec = T::comp(wv1, pp1);
        T::loadIdx(idcs, imin(c0 + 4 * W, NCm1), q, ii1);
        T::loadPrm(prm, imin(c0 + 4 * W, NCm1), q, pp1);
        e += ((c0 + W <= NCm1) ? 1.0f : 0.0f) * ec;

        // step 2: compute c0+2W (wv2,pp2); gather c0+4W; refill slot2 <- c0+5W
        gath<T::NW>(baseg, ii1, jp, wv1);
        ec = T::comp(wv2, pp2);
        T::loadIdx(idcs, imin(c0 + 5 * W, NCm1), q, ii2);
        T::loadPrm(prm, imin(c0 + 5 * W, NCm1), q, pp2);
        e += ((c0 + 2 * W <= NCm1) ? 1.0f : 0.0f) * ec;

        c0 += 3 * W;
    }
    // epilogue: wv0/pp0 hold chunk c0, wv1/pp1 hold c0+W
    v2f ec = T::comp(wv0, pp0);
    e += ((c0 <= NCm1) ? 1.0f : 0.0f) * ec;
    ec = T::comp(wv1, pp1);
    e += ((c0 + W <= NCm1) ? 1.0f : 0.0f) * ec;
}

// ---------------- main: batch-group x XCD partitioned, type-specialized waves,
// ---------------- uint2 gathers, depth-3 idx+param prefetch. grid 1536, (256,6).
__global__ __launch_bounds__(256, 6) void energy_kernel(
    const unsigned int* __restrict__ pos8,
    const int*   __restrict__ bond_idcs,  const int* __restrict__ angle_idcs,
    const int*   __restrict__ improper_idcs, const int* __restrict__ proper_idcs,
    const float* __restrict__ bondP, const float* __restrict__ angleP,
    const float* __restrict__ impP,  const float* __restrict__ propP,
    float* __restrict__ out)
{
    const int lane = threadIdx.x & 63;
    const int q    = lane >> 2;                                          // term slot [0,16)
    const int jp   = lane & 3;                                           // batch-pair [0,4)
    const int wid  = __builtin_amdgcn_readfirstlane(threadIdx.x >> 6);   // scalar
    const int g    = blockIdx.x & 7;                                     // batch group == XCD
    const int wig  = (blockIdx.x >> 3) * 4 + wid;                        // wave-in-group [0,768)

    const unsigned int* __restrict__ baseg = pos8 + (size_t)g * GSTRIDE;

    v2f e = {0.0f, 0.0f};                        // energies for batches (2jp, 2jp+1)
    if (wig < OFF_A)                                 // bond cohort
        run_type<BondT,  WB_B, 38>(baseg, bond_idcs,     bondP,  wig,         q, jp, e);
    else if (wig < OFF_I)                            // angle cohort
        run_type<AngleT, WB_A, 23>(baseg, angle_idcs,    angleP, wig - OFF_A, q, jp, e);
    else if (wig < OFF_P)                            // improper cohort
        run_type<ImpT,   WB_I, 23>(baseg, improper_idcs, impP,   wig - OFF_I, q, jp, e);
    else                                             // proper cohort
        run_type<PropT,  WB_P, 26>(baseg, proper_idcs,   propP,  wig - OFF_P, q, jp, e);

    // reduce across the 16 term-slots (same jp): xor-butterfly strides 4..32
    #pragma unroll
    for (int s = 4; s <= 32; s <<= 1) {
        e.x += __shfl_xor(e.x, s);
        e.y += __shfl_xor(e.y, s);
    }

    __shared__ float2 red[4][4];
    if (lane < 4) red[wid][lane] = make_float2(e.x, e.y);
    __syncthreads();
    if (wid == 0 && lane < 4) {
        float sx = red[0][lane].x + red[1][lane].x + red[2][lane].x + red[3][lane].x;
        float sy = red[0][lane].y + red[1][lane].y + red[2][lane].y + red[3][lane].y;
        atomicAdd(&out[g * 8 + 2 * lane],     sx);
        atomicAdd(&out[g * 8 + 2 * lane + 1], sy);
    }
}

extern "C" void kernel_launch(void* const* d_in, const int* in_sizes, int n_in,
                              void* d_out, int out_size, void* d_ws, size_t ws_size,
                              hipStream_t stream) {
    const float* pos           = (const float*)d_in[0];
    const int*   bond_idcs     = (const int*)  d_in[1];
    const int*   bond_type     = (const int*)  d_in[2];
    const float* equ_bond      = (const float*)d_in[3];
    const float* k_bond        = (const float*)d_in[4];
    const int*   angle_idcs    = (const int*)  d_in[5];
    const int*   angle_type    = (const int*)  d_in[6];
    const float* equ_angle     = (const float*)d_in[7];
    const float* k_angle       = (const float*)d_in[8];
    const int*   improper_idcs = (const int*)  d_in[9];
    const int*   improper_type = (const int*)  d_in[10];
    const float* equ_improper  = (const float*)d_in[11];
    const float* k_improper    = (const float*)d_in[12];
    const int*   proper_idcs   = (const int*)  d_in[13];
    const float* proper_phase  = (const float*)d_in[14];
    const float* proper_const  = (const float*)d_in[15];
    const float* proper_mul    = (const float*)d_in[16];
    float* out = (float*)d_out;

    unsigned int* pos8  = (unsigned int*)d_ws;                       // 25.6 MB, group-major
    float2* bondP  = (float2*)((char*)d_ws + OFF_BONDP);             // 1.2 MB
    float2* angleP = (float2*)((char*)d_ws + OFF_ANGP);              // 1.6 MB
    float2* impP   = (float2*)((char*)d_ws + OFF_IMPP);             // 0.4 MB
    float4* propP  = (float4*)((char*)d_ws + OFF_PROPP);             // 1.6 MB

    // fused pre-pass: 3125 transpose tiles + 782 param-fuse blocks (+ out zero)
    pre_kernel<<<dim3(N_TILES + (N_ANGLE + 255) / 256), dim3(256), 0, stream>>>(
        pos, pos8,
        bond_type, equ_bond, k_bond,
        angle_type, equ_angle, k_angle,
        improper_type, equ_improper, k_improper,
        proper_const, proper_mul, proper_phase,
        bondP, angleP, impP, propP,
        out, out_size);

    energy_kernel<<<dim3(1536), dim3(256), 0, stream>>>(
        pos8, bond_idcs, angle_idcs, improper_idcs, proper_idcs,
        (const float*)bondP, (const float*)angleP, (const float*)impP, (const float*)propP,
        out);
}